// Round 1
// baseline (1237.727 us; speedup 1.0000x reference)
//
#include <hip/hip_runtime.h>

#define NN 100000

// ---------------- degree ----------------
__global__ void count_deg_kernel(const int* __restrict__ dst, float* __restrict__ deg, int E) {
    int e = blockIdx.x * blockDim.x + threadIdx.x;
    if (e < E) atomicAdd(&deg[dst[e]], 1.0f);
}

__global__ void dis_kernel(float* __restrict__ deg_dis, int N) {
    int i = blockIdx.x * blockDim.x + threadIdx.x;
    if (i < N) {
        float d = deg_dis[i] + 1.0f;   // + self loop; deg >= 1 always
        deg_dis[i] = rsqrtf(d);
    }
}

// ---------------- GEMM: h[N,F] = (relu?)x[N,K] @ W[K,F] ----------------
template<int K, int F, int ROWS, bool RELU>
__global__ __launch_bounds__(256) void gemm_kernel(const float* __restrict__ x,
                                                   const float* __restrict__ W,
                                                   float* __restrict__ h, int N) {
    __shared__ float sW[K * F];      // 32 KB for both layer shapes
    __shared__ float sX[ROWS * K];   // 8 KB
    const int tid = threadIdx.x;
    for (int i = tid; i < K * F; i += 256) sW[i] = W[i];
    const int row0 = blockIdx.x * ROWS;
    const int nrows = min(ROWS, N - row0);
    for (int i = tid; i < nrows * K; i += 256) {
        float v = x[(size_t)row0 * K + i];
        if (RELU) v = fmaxf(v, 0.0f);
        sX[i] = v;
    }
    __syncthreads();
    const int col = tid % F;
    for (int rr = tid / F; rr < nrows; rr += 256 / F) {
        float acc = 0.0f;
        #pragma unroll
        for (int k = 0; k < K; ++k) acc += sX[rr * K + k] * sW[k * F + col];
        h[(size_t)(row0 + rr) * F + col] = acc;
    }
}

// ---------------- init: out[i][c] = h[i][c]*dis[i]^2 + b[c] (self loop + bias) ----------------
template<int F>
__global__ void init_kernel(const float* __restrict__ h, const float* __restrict__ dis,
                            const float* __restrict__ b, float* __restrict__ out, int N) {
    long long idx = (long long)blockIdx.x * blockDim.x + threadIdx.x;
    if (idx >= (long long)N * F) return;
    int i = (int)(idx / F);
    int c = (int)(idx % F);
    float w = dis[i];
    out[idx] = h[idx] * (w * w) + b[c];
}

// ---------------- edge scatter: one wave per edge ----------------
template<int F>
__global__ void scatter_kernel(const int* __restrict__ src, const int* __restrict__ dst,
                               const float* __restrict__ dis, const float* __restrict__ h,
                               float* __restrict__ out, int E) {
    long long gtid = (long long)blockIdx.x * blockDim.x + threadIdx.x;
    int e = (int)(gtid >> 6);
    int lane = (int)(gtid & 63);
    if (e >= E) return;
    int s = src[e];
    int d = dst[e];
    float w = dis[s] * dis[d];
    const float* hs = h + (size_t)s * F;
    float* od = out + (size_t)d * F;
    #pragma unroll
    for (int c = lane; c < F; c += 64) atomicAdd(&od[c], hs[c] * w);
}

extern "C" void kernel_launch(void* const* d_in, const int* in_sizes, int n_in,
                              void* d_out, int out_size, void* d_ws, size_t ws_size,
                              hipStream_t stream) {
    const float* x  = (const float*)d_in[0];
    const int*   ei = (const int*)d_in[1];
    const float* W1 = (const float*)d_in[2];
    const float* b1 = (const float*)d_in[3];
    const float* W2 = (const float*)d_in[4];
    const float* b2 = (const float*)d_in[5];
    float* out = (float*)d_out;

    const int N = NN;
    const int E = in_sizes[1] / 2;
    const int* src = ei;
    const int* dst = ei + E;

    float* ws  = (float*)d_ws;
    float* dis = ws;                       // N floats (deg -> dis in place)
    float* h1  = ws + N;                   // N*128
    float* a1  = h1 + (size_t)N * 128;     // N*128
    float* h2  = h1;                       // reuse h1's space (N*64)

    // deg -> dis
    hipMemsetAsync(dis, 0, (size_t)N * sizeof(float), stream);
    count_deg_kernel<<<(E + 255) / 256, 256, 0, stream>>>(dst, dis, E);
    dis_kernel<<<(N + 255) / 256, 256, 0, stream>>>(dis, N);

    // layer 1
    gemm_kernel<64, 128, 32, false><<<(N + 31) / 32, 256, 0, stream>>>(x, W1, h1, N);
    {
        long long tot = (long long)N * 128;
        init_kernel<128><<<(int)((tot + 255) / 256), 256, 0, stream>>>(h1, dis, b1, a1, N);
    }
    {
        long long threads = (long long)E * 64;
        scatter_kernel<128><<<(int)((threads + 255) / 256), 256, 0, stream>>>(src, dst, dis, h1, a1, E);
    }

    // layer 2 (relu fused into GEMM input load)
    gemm_kernel<128, 64, 16, true><<<(N + 15) / 16, 256, 0, stream>>>(a1, W2, h2, N);
    {
        long long tot = (long long)N * 64;
        init_kernel<64><<<(int)((tot + 255) / 256), 256, 0, stream>>>(h2, dis, b2, out, N);
    }
    {
        long long threads = (long long)E * 64;
        scatter_kernel<64><<<(int)((threads + 255) / 256), 256, 0, stream>>>(src, dst, dis, h2, out, E);
    }
}

// Round 2
// 486.191 us; speedup vs baseline: 2.5458x; 2.5458x over previous
//
#include <hip/hip_runtime.h>

#define NN 100000
#define SCAN_B 256

// ---------------- degree histogram (int) ----------------
__global__ void hist_kernel(const int* __restrict__ dst, int* __restrict__ degcnt, int E) {
    int e = blockIdx.x * blockDim.x + threadIdx.x;
    if (e < E) atomicAdd(&degcnt[dst[e]], 1);
}

__global__ void dis_kernel(const int* __restrict__ degcnt, float* __restrict__ dis, int N) {
    int i = blockIdx.x * blockDim.x + threadIdx.x;
    if (i < N) dis[i] = rsqrtf((float)degcnt[i] + 1.0f);  // + self loop
}

// ---------------- exclusive prefix scan over degcnt -> row_start ----------------
__global__ void scan1_kernel(const int* __restrict__ degcnt, int* __restrict__ row_start,
                             int* __restrict__ blk_sums, int N) {
    __shared__ int sm[SCAN_B];
    int t = threadIdx.x, i = blockIdx.x * SCAN_B + t;
    int v = (i < N) ? degcnt[i] : 0;
    sm[t] = v; __syncthreads();
    for (int off = 1; off < SCAN_B; off <<= 1) {
        int x = (t >= off) ? sm[t - off] : 0; __syncthreads();
        sm[t] += x; __syncthreads();
    }
    if (i < N) row_start[i] = sm[t] - v;     // exclusive within block
    if (t == SCAN_B - 1) blk_sums[blockIdx.x] = sm[t];
}

__global__ void scan2_kernel(const int* __restrict__ blk_sums, int* __restrict__ blk_off, int nblk) {
    __shared__ int sm[SCAN_B];
    __shared__ int run;
    int t = threadIdx.x;
    if (t == 0) run = 0;
    __syncthreads();
    for (int base = 0; base < nblk; base += SCAN_B) {
        int i = base + t;
        int v = (i < nblk) ? blk_sums[i] : 0;
        sm[t] = v; __syncthreads();
        for (int off = 1; off < SCAN_B; off <<= 1) {
            int x = (t >= off) ? sm[t - off] : 0; __syncthreads();
            sm[t] += x; __syncthreads();
        }
        if (i < nblk) blk_off[i] = run + sm[t] - v;
        __syncthreads();
        if (t == 0) run += sm[SCAN_B - 1];
        __syncthreads();
    }
}

__global__ void scan3_kernel(int* __restrict__ row_start, const int* __restrict__ blk_off, int N, int E) {
    int i = blockIdx.x * SCAN_B + threadIdx.x;
    if (i < N) row_start[i] += blk_off[blockIdx.x];
    if (i == 0) row_start[N] = E;
}

// ---------------- CSR fill (src index + precomputed norm weight) ----------------
__global__ void fill_kernel(const int* __restrict__ src, const int* __restrict__ dst,
                            const float* __restrict__ dis, const int* __restrict__ row_start,
                            int* __restrict__ cursor, int* __restrict__ csr_src,
                            float* __restrict__ csr_w, int E) {
    int e = blockIdx.x * blockDim.x + threadIdx.x;
    if (e >= E) return;
    int s = src[e], d = dst[e];
    int pos = row_start[d] + atomicAdd(&cursor[d], 1);
    csr_src[pos] = s;
    csr_w[pos] = dis[s] * dis[d];
}

// ---------------- GEMM: h[N,F] = x[N,K] @ W[K,F] ----------------
template<int K, int F, int ROWS>
__global__ __launch_bounds__(256) void gemm_kernel(const float* __restrict__ x,
                                                   const float* __restrict__ W,
                                                   float* __restrict__ h, int N) {
    __shared__ float sW[K * F];
    __shared__ float sX[ROWS * K];
    const int tid = threadIdx.x;
    for (int i = tid; i < K * F; i += 256) sW[i] = W[i];
    const int row0 = blockIdx.x * ROWS;
    const int nrows = min(ROWS, N - row0);
    for (int i = tid; i < nrows * K; i += 256) sX[i] = x[(size_t)row0 * K + i];
    __syncthreads();
    const int col = tid % F;
    for (int rr = tid / F; rr < nrows; rr += 256 / F) {
        float acc = 0.0f;
        #pragma unroll
        for (int k = 0; k < K; ++k) acc += sX[rr * K + k] * sW[k * F + col];
        h[(size_t)(row0 + rr) * F + col] = acc;
    }
}

// ---------------- gather aggregation: one wave per (node, 64-col slice) ----------------
// out[d][col] = (relu?) ( h[d][col]*dis[d]^2 + b[col] + sum_{s in nbrs(d)} h[s][col]*w_sd )
template<int F, bool RELU>
__global__ __launch_bounds__(256) void gather_kernel(const float* __restrict__ h,
                                                     const float* __restrict__ dis,
                                                     const float* __restrict__ b,
                                                     const int* __restrict__ row_start,
                                                     const int* __restrict__ csr_src,
                                                     const float* __restrict__ csr_w,
                                                     float* __restrict__ out, int N) {
    const int wave = blockIdx.x * 4 + (threadIdx.x >> 6);
    const int lane = threadIdx.x & 63;
    int node, off;
    if (F == 128) { node = wave >> 1; off = (wave & 1) * 64; }
    else          { node = wave;      off = 0; }
    if (node >= N) return;
    const int col = off + lane;
    const int beg = row_start[node], end = row_start[node + 1];
    const float dd = dis[node];
    float acc = h[(size_t)node * F + col] * (dd * dd) + b[col];
    int j = beg;
    for (; j + 3 < end; j += 4) {
        int s0 = csr_src[j], s1 = csr_src[j + 1], s2 = csr_src[j + 2], s3 = csr_src[j + 3];
        float w0 = csr_w[j], w1 = csr_w[j + 1], w2 = csr_w[j + 2], w3 = csr_w[j + 3];
        float v0 = h[(size_t)s0 * F + col];
        float v1 = h[(size_t)s1 * F + col];
        float v2 = h[(size_t)s2 * F + col];
        float v3 = h[(size_t)s3 * F + col];
        acc += v0 * w0; acc += v1 * w1; acc += v2 * w2; acc += v3 * w3;
    }
    for (; j < end; ++j) acc += h[(size_t)csr_src[j] * F + col] * csr_w[j];
    out[(size_t)node * F + col] = RELU ? fmaxf(acc, 0.0f) : acc;
}

extern "C" void kernel_launch(void* const* d_in, const int* in_sizes, int n_in,
                              void* d_out, int out_size, void* d_ws, size_t ws_size,
                              hipStream_t stream) {
    const float* x  = (const float*)d_in[0];
    const int*   ei = (const int*)d_in[1];
    const float* W1 = (const float*)d_in[2];
    const float* b1 = (const float*)d_in[3];
    const float* W2 = (const float*)d_in[4];
    const float* b2 = (const float*)d_in[5];
    float* out = (float*)d_out;

    const int N = NN;
    const int E = in_sizes[1] / 2;
    const int* src = ei;
    const int* dst = ei + E;
    const int nblk = (N + SCAN_B - 1) / SCAN_B;   // 391

    // workspace layout (4-byte words)
    float* ws = (float*)d_ws;
    float* dis      = ws;                                  // N
    int*   degcnt   = (int*)(ws + N);                      // N
    int*   row_start= (int*)(ws + 2 * N);                  // N+1
    int*   cursor   = (int*)(ws + 3 * N + 64);             // N
    int*   blk_sums = (int*)(ws + 4 * N + 64);             // <=1024
    int*   blk_off  = (int*)(ws + 4 * N + 64 + 1024);      // <=1024
    int*   csr_src  = (int*)(ws + 4 * N + 64 + 2048);      // E
    float* csr_w    = (float*)(ws + 4 * N + 64 + 2048 + E);// E
    float* h1       = ws + 4 * N + 64 + 2048 + 2 * (size_t)E;       // N*128
    float* a1       = h1 + (size_t)N * 128;                         // N*128
    float* h2       = h1;  // h1 dead after gather1; reuse for N*64

    // ---- degree + CSR build ----
    hipMemsetAsync(degcnt, 0, (size_t)N * sizeof(int), stream);
    hipMemsetAsync(cursor, 0, (size_t)N * sizeof(int), stream);
    hist_kernel<<<(E + 255) / 256, 256, 0, stream>>>(dst, degcnt, E);
    dis_kernel<<<(N + 255) / 256, 256, 0, stream>>>(degcnt, dis, N);
    scan1_kernel<<<nblk, SCAN_B, 0, stream>>>(degcnt, row_start, blk_sums, N);
    scan2_kernel<<<1, SCAN_B, 0, stream>>>(blk_sums, blk_off, nblk);
    scan3_kernel<<<nblk, SCAN_B, 0, stream>>>(row_start, blk_off, N, E);
    fill_kernel<<<(E + 255) / 256, 256, 0, stream>>>(src, dst, dis, row_start, cursor, csr_src, csr_w, E);

    // ---- layer 1 ----
    gemm_kernel<64, 128, 32><<<(N + 31) / 32, 256, 0, stream>>>(x, W1, h1, N);
    {   // gather with fused self-loop + bias + relu
        int waves = 2 * N;
        gather_kernel<128, true><<<(waves + 3) / 4, 256, 0, stream>>>(h1, dis, b1, row_start, csr_src, csr_w, a1, N);
    }

    // ---- layer 2 ----
    gemm_kernel<128, 64, 16><<<(N + 15) / 16, 256, 0, stream>>>(a1, W2, h2, N);
    {
        int waves = N;
        gather_kernel<64, false><<<(waves + 3) / 4, 256, 0, stream>>>(h2, dis, b2, row_start, csr_src, csr_w, out, N);
    }
}

// Round 3
// 412.759 us; speedup vs baseline: 2.9987x; 1.1779x over previous
//
#include <hip/hip_runtime.h>
#include <hip/hip_fp16.h>

#define NN 100000
#define SCAN_B 256

// ---------------- degree histogram (int) ----------------
__global__ void hist_kernel(const int* __restrict__ dst, int* __restrict__ degcnt, int E) {
    int e = blockIdx.x * blockDim.x + threadIdx.x;
    if (e < E) atomicAdd(&degcnt[dst[e]], 1);
}

__global__ void dis_kernel(const int* __restrict__ degcnt, float* __restrict__ dis, int N) {
    int i = blockIdx.x * blockDim.x + threadIdx.x;
    if (i < N) dis[i] = rsqrtf((float)degcnt[i] + 1.0f);  // + self loop
}

// ---------------- exclusive prefix scan over degcnt -> row_start ----------------
__global__ void scan1_kernel(const int* __restrict__ degcnt, int* __restrict__ row_start,
                             int* __restrict__ blk_sums, int N) {
    __shared__ int sm[SCAN_B];
    int t = threadIdx.x, i = blockIdx.x * SCAN_B + t;
    int v = (i < N) ? degcnt[i] : 0;
    sm[t] = v; __syncthreads();
    for (int off = 1; off < SCAN_B; off <<= 1) {
        int x = (t >= off) ? sm[t - off] : 0; __syncthreads();
        sm[t] += x; __syncthreads();
    }
    if (i < N) row_start[i] = sm[t] - v;
    if (t == SCAN_B - 1) blk_sums[blockIdx.x] = sm[t];
}

__global__ void scan2_kernel(const int* __restrict__ blk_sums, int* __restrict__ blk_off, int nblk) {
    __shared__ int sm[SCAN_B];
    __shared__ int run;
    int t = threadIdx.x;
    if (t == 0) run = 0;
    __syncthreads();
    for (int base = 0; base < nblk; base += SCAN_B) {
        int i = base + t;
        int v = (i < nblk) ? blk_sums[i] : 0;
        sm[t] = v; __syncthreads();
        for (int off = 1; off < SCAN_B; off <<= 1) {
            int x = (t >= off) ? sm[t - off] : 0; __syncthreads();
            sm[t] += x; __syncthreads();
        }
        if (i < nblk) blk_off[i] = run + sm[t] - v;
        __syncthreads();
        if (t == 0) run += sm[SCAN_B - 1];
        __syncthreads();
    }
}

__global__ void scan3_kernel(int* __restrict__ row_start, const int* __restrict__ blk_off, int N, int E) {
    int i = blockIdx.x * SCAN_B + threadIdx.x;
    if (i < N) row_start[i] += blk_off[blockIdx.x];
    if (i == 0) row_start[N] = E;
}

// ---------------- CSR fill (src index + precomputed norm weight) ----------------
__global__ void fill_kernel(const int* __restrict__ src, const int* __restrict__ dst,
                            const float* __restrict__ dis, const int* __restrict__ row_start,
                            int* __restrict__ cursor, int* __restrict__ csr_src,
                            float* __restrict__ csr_w, int E) {
    int e = blockIdx.x * blockDim.x + threadIdx.x;
    if (e >= E) return;
    int s = src[e], d = dst[e];
    int pos = row_start[d] + atomicAdd(&cursor[d], 1);
    csr_src[pos] = s;
    csr_w[pos] = dis[s] * dis[d];
}

// ---------------- fp32 -> fp16 table conversion (4 elems/thread) ----------------
__global__ void cvt_kernel(const float* __restrict__ in, __half* __restrict__ out, long long n4) {
    long long i = (long long)blockIdx.x * blockDim.x + threadIdx.x;
    if (i >= n4) return;
    float4 v = ((const float4*)in)[i];
    __half2* o = (__half2*)out;
    o[2 * i]     = __floats2half2_rn(v.x, v.y);
    o[2 * i + 1] = __floats2half2_rn(v.z, v.w);
}

// ---------------- GEMM: h[N,F] = x[N,K] @ W[K,F] (+bias, relu) ----------------
template<int K, int F, int ROWS, bool BIASRELU, typename OutT>
__global__ __launch_bounds__(256) void gemm_kernel(const float* __restrict__ x,
                                                   const float* __restrict__ W,
                                                   const float* __restrict__ bias,
                                                   OutT* __restrict__ h, int N) {
    __shared__ float sW[K * F];
    __shared__ float sX[ROWS * K];
    const int tid = threadIdx.x;
    for (int i = tid; i < K * F; i += 256) sW[i] = W[i];
    const int row0 = blockIdx.x * ROWS;
    const int nrows = min(ROWS, N - row0);
    for (int i = tid; i < nrows * K; i += 256) sX[i] = x[(size_t)row0 * K + i];
    __syncthreads();
    const int col = tid % F;
    for (int rr = tid / F; rr < nrows; rr += 256 / F) {
        float acc = 0.0f;
        #pragma unroll
        for (int k = 0; k < K; ++k) acc += sX[rr * K + k] * sW[k * F + col];
        if (BIASRELU) acc = fmaxf(acc + bias[col], 0.0f);
        size_t idx = (size_t)(row0 + rr) * F + col;
        if constexpr (sizeof(OutT) == 2) h[idx] = __float2half(acc);
        else                             h[idx] = acc;
    }
}

// ---------------- gather over 64-col fp16 table, one wave per node ----------------
// out[d][lane] = tab[d][lane]*dis[d]^2 (+b[lane]) + sum_{s in nbrs(d)} tab[s][lane]*w
template<bool BIAS>
__global__ __launch_bounds__(256) void gather64_kernel(const __half* __restrict__ tab,
                                                       const float* __restrict__ dis,
                                                       const float* __restrict__ b,
                                                       const int* __restrict__ row_start,
                                                       const int* __restrict__ csr_src,
                                                       const float* __restrict__ csr_w,
                                                       float* __restrict__ out, int N) {
    const int node = blockIdx.x * 4 + (threadIdx.x >> 6);
    const int lane = threadIdx.x & 63;
    if (node >= N) return;
    const int beg = row_start[node], end = row_start[node + 1];
    const float dd = dis[node];
    float acc = __half2float(tab[(size_t)node * 64 + lane]) * (dd * dd);
    if (BIAS) acc += b[lane];
    int j = beg;
    for (; j + 3 < end; j += 4) {
        int s0 = csr_src[j],     s1 = csr_src[j + 1];
        int s2 = csr_src[j + 2], s3 = csr_src[j + 3];
        float w0 = csr_w[j],     w1 = csr_w[j + 1];
        float w2 = csr_w[j + 2], w3 = csr_w[j + 3];
        float v0 = __half2float(tab[(size_t)s0 * 64 + lane]);
        float v1 = __half2float(tab[(size_t)s1 * 64 + lane]);
        float v2 = __half2float(tab[(size_t)s2 * 64 + lane]);
        float v3 = __half2float(tab[(size_t)s3 * 64 + lane]);
        acc += v0 * w0; acc += v1 * w1; acc += v2 * w2; acc += v3 * w3;
    }
    for (; j < end; ++j) acc += __half2float(tab[(size_t)csr_src[j] * 64 + lane]) * csr_w[j];
    out[(size_t)node * 64 + lane] = acc;
}

extern "C" void kernel_launch(void* const* d_in, const int* in_sizes, int n_in,
                              void* d_out, int out_size, void* d_ws, size_t ws_size,
                              hipStream_t stream) {
    const float* x  = (const float*)d_in[0];
    const int*   ei = (const int*)d_in[1];
    const float* W1 = (const float*)d_in[2];
    const float* b1 = (const float*)d_in[3];
    const float* W2 = (const float*)d_in[4];
    const float* b2 = (const float*)d_in[5];
    float* out = (float*)d_out;

    const int N = NN;
    const int E = in_sizes[1] / 2;
    const int* src = ei;
    const int* dst = ei + E;
    const int nblk = (N + SCAN_B - 1) / SCAN_B;

    // workspace layout (4-byte words)
    float* ws = (float*)d_ws;
    float*  dis       = ws;                                   // N
    int*    degcnt    = (int*)(ws + N);                       // N
    int*    row_start = (int*)(ws + 2 * N);                   // N+1 (padded)
    int*    cursor    = (int*)(ws + 3 * N + 64);              // N
    int*    blk_sums  = (int*)(ws + 4 * N + 64);              // <=1024
    int*    blk_off   = (int*)(ws + 4 * N + 64 + 1024);       // <=1024
    int*    csr_src   = (int*)(ws + 4 * N + 64 + 2048);       // E
    float*  csr_w     = (float*)(ws + 4 * N + 64 + 2048 + E); // E
    float*  base      = ws + 4 * N + 64 + 2048 + 2 * (size_t)E;
    __half* xh        = (__half*)base;                        // N*64 halves = N*32 words
    __half* zh        = (__half*)(base + (size_t)N * 32);     // N*64 halves = N*32 words
    float*  agg       = base + (size_t)N * 64;                // N*64 floats
    float*  h1        = agg + (size_t)N * 64;                 // N*128 floats

    // ---- degree + CSR build ----
    hipMemsetAsync(degcnt, 0, (size_t)N * sizeof(int), stream);
    hipMemsetAsync(cursor, 0, (size_t)N * sizeof(int), stream);
    hist_kernel<<<(E + 255) / 256, 256, 0, stream>>>(dst, degcnt, E);
    dis_kernel<<<(N + 255) / 256, 256, 0, stream>>>(degcnt, dis, N);
    scan1_kernel<<<nblk, SCAN_B, 0, stream>>>(degcnt, row_start, blk_sums, N);
    scan2_kernel<<<1, SCAN_B, 0, stream>>>(blk_sums, blk_off, nblk);
    scan3_kernel<<<nblk, SCAN_B, 0, stream>>>(row_start, blk_off, N, E);
    fill_kernel<<<(E + 255) / 256, 256, 0, stream>>>(src, dst, dis, row_start, cursor, csr_src, csr_w, E);

    // ---- layer 1: agg = A_hat @ X (64 cols, fp16 table), h1 = relu(agg@W1 + b1) ----
    {
        long long n4 = (long long)N * 64 / 4;
        cvt_kernel<<<(int)((n4 + 255) / 256), 256, 0, stream>>>(x, xh, n4);
    }
    gather64_kernel<false><<<(N + 3) / 4, 256, 0, stream>>>(xh, dis, nullptr, row_start, csr_src, csr_w, agg, N);
    gemm_kernel<64, 128, 32, true, float><<<(N + 31) / 32, 256, 0, stream>>>(agg, W1, b1, h1, N);

    // ---- layer 2: zh = h1@W2 (fp16), out = A_hat @ zh + b2 ----
    gemm_kernel<128, 64, 16, false, __half><<<(N + 15) / 16, 256, 0, stream>>>(h1, W2, nullptr, zh, N);
    gather64_kernel<true><<<(N + 3) / 4, 256, 0, stream>>>(zh, dis, b2, row_start, csr_src, csr_w, out, N);
}